// Round 1
// baseline (140.885 us; speedup 1.0000x reference)
//
#include <hip/hip_runtime.h>

// l=3 real spherical-harmonic polynomials, 7 per atom, over flat atom stream.
// Atom a: reads in[3a..3a+2], writes out[7a..7a+6].
// Memory-bound (~800 MB traffic). LDS-staged for fully coalesced float4 I/O.

#define BLOCK 256
#define ATOMS_PER_BLOCK 1024
#define IN_F4_PER_BLOCK 768   // 1024 atoms * 3 floats / 4
#define OUT_F4_PER_BLOCK 1792 // 1024 atoms * 7 floats / 4

__global__ __launch_bounds__(BLOCK) void yl3_kernel(const float4* __restrict__ in4,
                                                    float4* __restrict__ out4,
                                                    int n_in4, int n_out4) {
    __shared__ float4 lds4[OUT_F4_PER_BLOCK];  // 28672 B, reused in/out
    float* lds = (float*)lds4;
    const int t = threadIdx.x;
    const int blk = blockIdx.x;

    // Phase 1: coalesced global -> LDS input load (768 float4 per block)
    const int in_base = blk * IN_F4_PER_BLOCK;
#pragma unroll
    for (int j = 0; j < 3; ++j) {
        const int l = t + BLOCK * j;
        const int g = in_base + l;
        if (g < n_in4) lds4[l] = in4[g];
    }
    __syncthreads();

    // Phase 2: each thread pulls 4 atoms' coords into registers
    float xs[4], ys[4], zs[4];
#pragma unroll
    for (int j = 0; j < 4; ++j) {
        const int a = t + BLOCK * j;
        xs[j] = lds[a * 3 + 0];
        ys[j] = lds[a * 3 + 1];
        zs[j] = lds[a * 3 + 2];
    }
    __syncthreads();  // all input consumed before LDS reuse

    // Phase 3: compute 7 components per atom, write to LDS (stride-7 words: conflict-free)
#pragma unroll
    for (int j = 0; j < 4; ++j) {
        const float x = xs[j], y = ys[j], z = zs[j];
        const float x2 = x * x, y2 = y * y, z2 = z * z;
        const float x2my2 = x2 - y2;
        const float r2 = x2 + y2 + z2;
        const float inv3 = 1.0f / (r2 * sqrtf(r2));
        const int a = t + BLOCK * j;
        float* o = &lds[a * 7];
        o[0] = (3.0f * x2 - y2) * y * inv3;
        o[1] = x * y * z * inv3;
        o[2] = (4.0f * z2 - x2my2) * y * inv3;
        o[3] = (2.0f * z2 - 3.0f * x2my2) * z * inv3;
        o[4] = (4.0f * z2 - x2my2) * x * inv3;
        o[5] = z * x2my2 * inv3;
        o[6] = x * (x2 - 3.0f * y2) * inv3;
    }
    __syncthreads();

    // Phase 4: coalesced LDS -> global store (1792 float4 per block)
    const int out_base = blk * OUT_F4_PER_BLOCK;
#pragma unroll
    for (int j = 0; j < 7; ++j) {
        const int l = t + BLOCK * j;
        const int g = out_base + l;
        if (g < n_out4) out4[g] = lds4[l];
    }
}

extern "C" void kernel_launch(void* const* d_in, const int* in_sizes, int n_in,
                              void* d_out, int out_size, void* d_ws, size_t ws_size,
                              hipStream_t stream) {
    const float* in = (const float*)d_in[0];
    float* out = (float*)d_out;

    const long long n_in_f = in_sizes[0];      // 60,000,000
    const long long atoms = n_in_f / 3;        // 20,000,000
    const int n_in4 = (int)(n_in_f / 4);       // 15,000,000
    const int n_out4 = out_size / 4;           // 35,000,000
    const int blocks = (int)((atoms + ATOMS_PER_BLOCK - 1) / ATOMS_PER_BLOCK);

    yl3_kernel<<<blocks, BLOCK, 0, stream>>>((const float4*)in, (float4*)out,
                                             n_in4, n_out4);
}

// Round 3
// 131.001 us; speedup vs baseline: 1.0755x; 1.0755x over previous
//
#include <hip/hip_runtime.h>

// l=3 real spherical-harmonic polynomials, 7 per atom, over flat atom stream.
// Atom a: reads in[3a..3a+2], writes out[7a..7a+6].
// Memory-bound (~800 MB traffic, read 240 / write 560).
// LDS-staged for fully coalesced float4 I/O; nontemporal hints since both
// streams are touch-once; split in/out LDS regions -> only 2 barriers.

typedef float f4 __attribute__((ext_vector_type(4)));  // clang vector: OK for nontemporal builtins

#define BLOCK 256
#define ATOMS_PER_BLOCK 1024
#define IN_F4_PER_BLOCK 768   // 1024 atoms * 3 floats / 4
#define OUT_F4_PER_BLOCK 1792 // 1024 atoms * 7 floats / 4

__global__ __launch_bounds__(BLOCK) void yl3_kernel(const f4* __restrict__ in4,
                                                    f4* __restrict__ out4,
                                                    int n_in4, int n_out4) {
    __shared__ f4 lin4[IN_F4_PER_BLOCK];    // 12288 B
    __shared__ f4 lout4[OUT_F4_PER_BLOCK];  // 28672 B  (40 KB total -> 4 blk/CU)
    float* lin = (float*)lin4;
    float* lout = (float*)lout4;
    const int t = threadIdx.x;
    const int blk = blockIdx.x;

    // Phase 1: coalesced global -> LDS input load (768 float4 per block)
    const int in_base = blk * IN_F4_PER_BLOCK;
#pragma unroll
    for (int j = 0; j < 3; ++j) {
        const int l = t + BLOCK * j;
        const int g = in_base + l;
        if (g < n_in4) lin4[l] = __builtin_nontemporal_load(&in4[g]);
    }
    __syncthreads();

    // Phase 2+3: per-atom compute, LDS write at word-stride 7 (conflict-free)
#pragma unroll
    for (int j = 0; j < 4; ++j) {
        const int a = t + BLOCK * j;
        const float x = lin[a * 3 + 0];
        const float y = lin[a * 3 + 1];
        const float z = lin[a * 3 + 2];
        const float x2 = x * x, y2 = y * y, z2 = z * z;
        const float x2my2 = x2 - y2;
        const float r2 = x2 + y2 + z2;
        const float inv3 = 1.0f / (r2 * sqrtf(r2));
        float* o = &lout[a * 7];
        o[0] = (3.0f * x2 - y2) * y * inv3;
        o[1] = x * y * z * inv3;
        o[2] = (4.0f * z2 - x2my2) * y * inv3;
        o[3] = (2.0f * z2 - 3.0f * x2my2) * z * inv3;
        o[4] = (4.0f * z2 - x2my2) * x * inv3;
        o[5] = z * x2my2 * inv3;
        o[6] = x * (x2 - 3.0f * y2) * inv3;
    }
    __syncthreads();

    // Phase 4: coalesced LDS -> global nontemporal store (1792 float4 per block)
    const int out_base = blk * OUT_F4_PER_BLOCK;
#pragma unroll
    for (int j = 0; j < 7; ++j) {
        const int l = t + BLOCK * j;
        const int g = out_base + l;
        if (g < n_out4) __builtin_nontemporal_store(lout4[l], &out4[g]);
    }
}

extern "C" void kernel_launch(void* const* d_in, const int* in_sizes, int n_in,
                              void* d_out, int out_size, void* d_ws, size_t ws_size,
                              hipStream_t stream) {
    const float* in = (const float*)d_in[0];
    float* out = (float*)d_out;

    const long long n_in_f = in_sizes[0];      // 60,000,000
    const long long atoms = n_in_f / 3;        // 20,000,000
    const int n_in4 = (int)(n_in_f / 4);       // 15,000,000
    const int n_out4 = out_size / 4;           // 35,000,000
    const int blocks = (int)((atoms + ATOMS_PER_BLOCK - 1) / ATOMS_PER_BLOCK);

    yl3_kernel<<<blocks, BLOCK, 0, stream>>>((const f4*)in, (f4*)out,
                                             n_in4, n_out4);
}